// Round 13
// baseline (136.027 us; speedup 1.0000x reference)
//
#include <hip/hip_runtime.h>

#define NN 100000
#define NE 1600000
#define HID 128
#define NBUCK 1563          // ceil(NN/64), 64-node buckets
#define CAP 1280            // csr slots per bucket (Poisson(1024)+8 sigma)
#define STP 130             // padded LDS stride (f32 words) for min-state
#define SENT 3.0e38f
#define CH 16384            // edges per sort chunk
#define NCH 98              // ceil(NE/CH)
#define ENCB 391            // encoder blocks (256 rows each)

typedef float f32x4 __attribute__((ext_vector_type(4)));
typedef __bf16 bf16x8 __attribute__((ext_vector_type(8)));
typedef unsigned short u16x8 __attribute__((ext_vector_type(8)));

static __device__ __forceinline__ unsigned short f2bf(float f) {
  union { float f; unsigned u; } v; v.f = f;
  unsigned u = v.u;
  return (unsigned short)((u + 0x7FFFu + ((u >> 16) & 1u)) >> 16);
}

static __device__ __forceinline__ f32x4 mfma_bf16(u16x8 a, u16x8 b, f32x4 c) {
  return __builtin_amdgcn_mfma_f32_16x16x32_bf16(
      __builtin_bit_cast(bf16x8, a), __builtin_bit_cast(bf16x8, b), c, 0, 0, 0);
}

// edge_index may arrive as int32 or int64 (values < 2^31, little-endian).
static __device__ __forceinline__ int gidx(const int* __restrict__ ei, int is64, long long pos) {
  return is64 ? ei[pos * 2] : ei[pos];
}
// inline dtype detection: for int64, hi-words of src[0..63] are all zero
static __device__ __forceinline__ int detect64(const int* __restrict__ ei, int tid) {
  unsigned long long bl = __ballot(ei[2 * (tid & 63) + 1] == 0);
  return (bl == ~0ull) ? 1 : 0;
}

// ---------------- one-time prep: padded-bf16 weight image + vprep + gcursor init ----------------
// Wb[m][j*136+k] = bf16(W_m[k][j]);  vprep[k] = sum_j W_upd[128+k][j]*W_dec[j];  gcursor[b]=b*CAP
__global__ __launch_bounds__(512) void k_prepw(const float* __restrict__ Wenc,
    const float* __restrict__ Wmsg, const float* __restrict__ Wupd,
    const float* __restrict__ Wdec, unsigned short* __restrict__ Wb,
    float* __restrict__ vprep, int* __restrict__ gcursor) {
  int b = blockIdx.x;
  int t = threadIdx.x;
  if (b == 96) {
    if (t < 128) {
      const float* row = Wupd + (size_t)(128 + t) * 128;
      float s = 0.f;
#pragma unroll 8
      for (int j = 0; j < 128; ++j) s = fmaf(row[j], Wdec[j], s);
      vprep[t] = s;
    }
    for (int i = t; i < NBUCK; i += 512) gcursor[i] = i * CAP;
    return;
  }
  int i = b * 512 + t;                        // 0..49151
  int m = i >> 14, idx = i & 16383;
  const float* src = (m == 0) ? Wenc : ((m == 1) ? Wmsg : Wupd);
  int k = idx >> 7, j = idx & 127;
  Wb[m * 17408 + j * 136 + k] = f2bf(src[idx]);
}

// ---------------- encoder + message projection + update-top decode ----------------
// One weight matrix staged at a time (34.8 KB) -> ~71 KB LDS -> 2 blocks/CU.
// Both row-groups' h fragments live in registers across stages.
__global__ __launch_bounds__(512, 4) void k_enc2(const float* __restrict__ x,
    const float* __restrict__ benc, const float* __restrict__ bupd,
    const float* __restrict__ Wdec, const unsigned short* __restrict__ Wb,
    unsigned* __restrict__ mNp, float* __restrict__ hdec) {
  __shared__ __align__(16) unsigned short Wt[17408];        // 34.8 KB (one matrix)
  __shared__ unsigned short bounce[8][16 * 136];            // 34.8 KB
  __shared__ float bshE[128];
  __shared__ float bshU[128];
  __shared__ float wdsh[128];
  int tid = threadIdx.x;
  if (tid < 128) { bshE[tid] = benc[tid]; bshU[tid] = bupd[tid]; wdsh[tid] = Wdec[tid]; }

  int wave = tid >> 6, lane = tid & 63;
  int l15 = lane & 15, lg = lane >> 4;
  f32x4 zero = {0.f, 0.f, 0.f, 0.f};
  u16x8 haG[2][4];                                          // h frags for both groups

  // ---- stage E: h = relu(x @ W_enc + b_enc) ----
  for (int i = tid; i < 2176; i += 512)
    ((uint4*)Wt)[i] = ((const uint4*)Wb)[i];
  __syncthreads();
#pragma unroll
  for (int g = 0; g < 2; ++g) {
    int rowBase = blockIdx.x * 256 + g * 128 + wave * 16;
    int nodeA = rowBase + l15; if (nodeA > NN - 1) nodeA = NN - 1;
    u16x8 af[4];
#pragma unroll
    for (int kt = 0; kt < 4; ++kt) {
      const float* px = x + (long long)nodeA * HID + kt * 32 + lg * 8;
      f32x4 a0 = *(const f32x4*)px;
      f32x4 a1 = *(const f32x4*)(px + 4);
      u16x8 t;
      t[0] = f2bf(a0[0]); t[1] = f2bf(a0[1]); t[2] = f2bf(a0[2]); t[3] = f2bf(a0[3]);
      t[4] = f2bf(a1[0]); t[5] = f2bf(a1[1]); t[6] = f2bf(a1[2]); t[7] = f2bf(a1[3]);
      af[kt] = t;
    }
    f32x4 acc[8];
#pragma unroll
    for (int nt = 0; nt < 8; ++nt) acc[nt] = zero;
#pragma unroll
    for (int kt = 0; kt < 4; ++kt)
#pragma unroll
      for (int nt = 0; nt < 8; ++nt) {
        u16x8 bfv = *(const u16x8*)&Wt[(nt * 16 + l15) * 136 + kt * 32 + lg * 8];
        acc[nt] = mfma_bf16(af[kt], bfv, acc[nt]);
      }
#pragma unroll
    for (int nt = 0; nt < 8; ++nt) {
      int j = nt * 16 + l15;
      float bj = bshE[j];
#pragma unroll
      for (int r = 0; r < 4; ++r) {
        float v = acc[nt][r] + bj;
        v = v > 0.f ? v : 0.f;
        bounce[wave][(lg * 4 + r) * 136 + j] = f2bf(v);
      }
    }
    asm volatile("s_waitcnt lgkmcnt(0)" ::: "memory");
    __builtin_amdgcn_sched_barrier(0);
#pragma unroll
    for (int kt = 0; kt < 4; ++kt)
      haG[g][kt] = *(const u16x8*)&bounce[wave][l15 * 136 + kt * 32 + lg * 8];
    asm volatile("s_waitcnt lgkmcnt(0)" ::: "memory");
    __builtin_amdgcn_sched_barrier(0);
  }
  __syncthreads();

  // ---- stage M: mN = h @ W_msg, permuted store ----
  for (int i = tid; i < 2176; i += 512)
    ((uint4*)Wt)[i] = ((const uint4*)Wb)[2176 + i];
  __syncthreads();
#pragma unroll
  for (int g = 0; g < 2; ++g) {
    int rowBase = blockIdx.x * 256 + g * 128 + wave * 16;
    f32x4 acc2[8];
#pragma unroll
    for (int nt = 0; nt < 8; ++nt) acc2[nt] = zero;
#pragma unroll
    for (int kt = 0; kt < 4; ++kt)
#pragma unroll
      for (int nt = 0; nt < 8; ++nt) {
        u16x8 bfv = *(const u16x8*)&Wt[(nt * 16 + l15) * 136 + kt * 32 + lg * 8];
        acc2[nt] = mfma_bf16(haG[g][kt], bfv, acc2[nt]);
      }
#pragma unroll
    for (int nt = 0; nt < 8; ++nt) {
      int j = nt * 16 + l15;
#pragma unroll
      for (int r = 0; r < 4; ++r)
        bounce[wave][(lg * 4 + r) * 136 + j] = f2bf(acc2[nt][r]);
    }
    asm volatile("s_waitcnt lgkmcnt(0)" ::: "memory");
    __builtin_amdgcn_sched_barrier(0);
    // permuted store: word l = col l | col(l+64)<<16
#pragma unroll 4
    for (int row = 0; row < 16; ++row) {
      int node = rowBase + row;
      if (node < NN) {
        unsigned lo = bounce[wave][row * 136 + lane];
        unsigned hi = bounce[wave][row * 136 + 64 + lane];
        mNp[(size_t)node * 64 + lane] = lo | (hi << 16);
      }
    }
    asm volatile("s_waitcnt lgkmcnt(0)" ::: "memory");
    __builtin_amdgcn_sched_barrier(0);
  }
  __syncthreads();

  // ---- stage U: hdec = (h @ W_upd_top + b_upd) . W_dec ----
  for (int i = tid; i < 2176; i += 512)
    ((uint4*)Wt)[i] = ((const uint4*)Wb)[4352 + i];
  __syncthreads();
#pragma unroll
  for (int g = 0; g < 2; ++g) {
    int rowBase = blockIdx.x * 256 + g * 128 + wave * 16;
    f32x4 acc3[8];
#pragma unroll
    for (int nt = 0; nt < 8; ++nt) acc3[nt] = zero;
#pragma unroll
    for (int kt = 0; kt < 4; ++kt)
#pragma unroll
      for (int nt = 0; nt < 8; ++nt) {
        u16x8 bfv = *(const u16x8*)&Wt[(nt * 16 + l15) * 136 + kt * 32 + lg * 8];
        acc3[nt] = mfma_bf16(haG[g][kt], bfv, acc3[nt]);
      }
    float hs0 = 0.f, hs1 = 0.f, hs2 = 0.f, hs3 = 0.f;
#pragma unroll
    for (int nt = 0; nt < 8; ++nt) {
      int j = nt * 16 + l15;
      float bu = bshU[j], wv = wdsh[j];
      hs0 += (acc3[nt][0] + bu) * wv;
      hs1 += (acc3[nt][1] + bu) * wv;
      hs2 += (acc3[nt][2] + bu) * wv;
      hs3 += (acc3[nt][3] + bu) * wv;
    }
#pragma unroll
    for (int m = 1; m < 16; m <<= 1) {
      hs0 += __shfl_xor(hs0, m);
      hs1 += __shfl_xor(hs1, m);
      hs2 += __shfl_xor(hs2, m);
      hs3 += __shfl_xor(hs3, m);
    }
    if (l15 == 0) {
      int n0 = rowBase + lg * 4;
      if (n0 + 3 < NN) {
        float4 st4; st4.x = hs0; st4.y = hs1; st4.z = hs2; st4.w = hs3;
        *(float4*)&hdec[n0] = st4;
      } else {
        if (n0 + 0 < NN) hdec[n0 + 0] = hs0;
        if (n0 + 1 < NN) hdec[n0 + 1] = hs1;
        if (n0 + 2 < NN) hdec[n0 + 2] = hs2;
        if (n0 + 3 < NN) hdec[n0 + 3] = hs3;
      }
    }
  }
}

// ---------------- sorted scatter into fixed-capacity bucket slots ----------------
// dst values cached in registers across the two passes (no dst re-read).
// entry u64: (src*64) 23b @0 | local(6b) @23 | ea_bf16(16b) @48
__global__ __launch_bounds__(512) void k_sortscatter(const int* __restrict__ ei,
    const float* __restrict__ ea, int* __restrict__ gcursor,
    unsigned long long* __restrict__ csr) {
  __shared__ unsigned gbase[NBUCK];
  __shared__ unsigned cnt[NBUCK];
  int tid = threadIdx.x;
  int chunk = blockIdx.x;
  long long base = (long long)chunk * CH;
  int n = (int)(((long long)NE - base < CH) ? ((long long)NE - base) : CH);
  int is64 = detect64(ei, tid);
  for (int i = tid; i < NBUCK; i += 512) cnt[i] = 0;
  __syncthreads();
  // pass 1: count this chunk's bucket sizes; keep dst in registers
  int dreg[CH / 512];
#pragma unroll
  for (int k = 0; k < CH / 512; ++k) {
    int i = k * 512 + tid;
    if (i < n) {
      int d = gidx(ei, is64, (long long)NE + base + i);
      dreg[k] = d;
      atomicAdd(&cnt[d >> 6], 1u);
    } else dreg[k] = -1;
  }
  __syncthreads();
  // claim contiguous runs in each bucket's slot region
  for (int b = tid; b < NBUCK; b += 512) {
    unsigned c = cnt[b];
    gbase[b] = c ? (unsigned)atomicAdd(&gcursor[b], (int)c) : 0u;
  }
  __syncthreads();
  for (int i = tid; i < NBUCK; i += 512) cnt[i] = 0;   // reuse as local cursor
  __syncthreads();
  // pass 2: write entries into the claimed runs (reads only src + ea)
#pragma unroll
  for (int k = 0; k < CH / 512; ++k) {
    int i = k * 512 + tid;
    int d = dreg[k];
    if (d >= 0) {
      int s = gidx(ei, is64, base + i);
      unsigned eab = f2bf(ea[base + i]);
      int b = d >> 6;
      unsigned lp = atomicAdd(&cnt[b], 1u);
      unsigned lo = (unsigned)(s << 6) | ((unsigned)(d & 63) << 23);
      csr[gbase[b] + lp] = (unsigned long long)lo | ((unsigned long long)eab << 48);
    }
  }
}

// ---------------- fused: edge min (native f32 LDS atomicMin) + decoder dot + sigmoid ----------------
// Wave-uniform csr processing: loop bounds scalarized so csr loads/decodes go to SALU/SMEM.
__global__ __launch_bounds__(512, 8) void k_msg(const unsigned* __restrict__ mNp,
    const float* __restrict__ Wmsg, const int* __restrict__ gcursor,
    const unsigned long long* __restrict__ csr, const float* __restrict__ bmsg,
    const float* __restrict__ vprep, const float* __restrict__ hdec,
    const float* __restrict__ bdec, float* __restrict__ out) {
  __shared__ float stf[64 * STP];     // 33.3 KB, padded stride
  int tid = threadIdx.x;
  int b = blockIdx.x;
  for (int i = tid; i < 64 * STP; i += 512) stf[i] = SENT;
  __syncthreads();

  int lane = tid & 63;
  int wv = tid >> 6;                     // 0..7
  int off = b * CAP, end = gcursor[b];
  int cntE = end - off;
  int per = (cntE + 7) >> 3;
  int i0 = off + wv * per;
  int i1 = i0 + per; if (i1 > end) i1 = end;
  // wave-uniform loop bounds -> scalar loads for csr
  int iu = __builtin_amdgcn_readfirstlane(i0);
  int ie = __builtin_amdgcn_readfirstlane(i1);
  float wl0 = Wmsg[128 * 128 + lane];
  float wl1 = Wmsg[128 * 128 + 64 + lane];

#define EDGE_DO(PK, VV) do { \
    int loc_ = (int)(((unsigned)(PK) >> 23) & 0x3Fu); \
    float ea_ = __uint_as_float((unsigned)((PK) >> 32) & 0xFFFF0000u); \
    float a0_ = fmaf(ea_, wl0, __uint_as_float((VV) << 16)); \
    float a1_ = fmaf(ea_, wl1, __uint_as_float((VV) & 0xFFFF0000u)); \
    atomicMin(&stf[loc_ * STP + lane], a0_); \
    atomicMin(&stf[loc_ * STP + 64 + lane], a1_); \
  } while (0)

  int i = iu;
  for (; i + 16 <= ie; i += 16) {
    unsigned long long pk[16];
#pragma unroll
    for (int j = 0; j < 16; ++j) pk[j] = csr[i + j];
    unsigned v[16];
#pragma unroll
    for (int j = 0; j < 16; ++j)
      v[j] = mNp[((unsigned)pk[j] & 0x7FFFFFu) + lane];
#pragma unroll
    for (int j = 0; j < 16; ++j) EDGE_DO(pk[j], v[j]);
  }
  for (; i + 4 <= ie; i += 4) {
    unsigned long long pk[4];
#pragma unroll
    for (int j = 0; j < 4; ++j) pk[j] = csr[i + j];
    unsigned v[4];
#pragma unroll
    for (int j = 0; j < 4; ++j)
      v[j] = mNp[((unsigned)pk[j] & 0x7FFFFFu) + lane];
#pragma unroll
    for (int j = 0; j < 4; ++j) EDGE_DO(pk[j], v[j]);
  }
  for (; i < ie; ++i) {
    unsigned long long pk = csr[i];
    unsigned v = mNp[((unsigned)pk & 0x7FFFFFu) + lane];
    EDGE_DO(pk, v);
  }
#undef EDGE_DO
  __syncthreads();

  // ---- phase 2: out[node] = sigmoid((agg+bmsg).v + hdec + bdec) ----
  float vl0 = vprep[lane], vl1 = vprep[64 + lane];
  float bm0 = bmsg[lane], bm1 = bmsg[64 + lane];
  float bd = *bdec;
#pragma unroll
  for (int q = 0; q < 8; ++q) {
    int loc = (wv << 3) + q;
    float s0 = stf[loc * STP + lane];
    float s1 = stf[loc * STP + 64 + lane];
    float ps = ((s0 < 1.0e30f) ? (s0 + bm0) * vl0 : 0.f)
             + ((s1 < 1.0e30f) ? (s1 + bm1) * vl1 : 0.f);
#pragma unroll
    for (int m = 1; m < 64; m <<= 1) ps += __shfl_xor(ps, m);
    if (lane == 0) {
      int node = (b << 6) + loc;
      if (node < NN)
        out[node] = 1.f / (1.f + expf(-(ps + hdec[node] + bd)));
    }
  }
}

extern "C" void kernel_launch(void* const* d_in, const int* in_sizes, int n_in,
                              void* d_out, int out_size, void* d_ws, size_t ws_size,
                              hipStream_t stream) {
  const float* x    = (const float*)d_in[0];
  const int*   ei   = (const int*)d_in[1];
  const float* ea   = (const float*)d_in[2];
  const float* Wenc = (const float*)d_in[3];
  const float* benc = (const float*)d_in[4];
  const float* Wmsg = (const float*)d_in[5];
  const float* bmsg = (const float*)d_in[6];
  const float* Wupd = (const float*)d_in[7];
  const float* bupd = (const float*)d_in[8];
  const float* Wdec = (const float*)d_in[9];
  const float* bdec = (const float*)d_in[10];
  float* out = (float*)d_out;

  // workspace carve (total ~42.2 MiB, well below the empirically-safe 65.2 MB)
  char* w = (char*)d_ws;
  auto alloc = [&](size_t bytes) { char* p = w; w += (bytes + 255) & ~(size_t)255; return p; };
  unsigned* mNp        = (unsigned*)alloc((size_t)NN * 64 * 4);             // 25.6 MB
  unsigned long long* csr = (unsigned long long*)alloc((size_t)NBUCK * CAP * 8); // 16.0 MB
  unsigned short* Wb = (unsigned short*)alloc(3 * 17408 * 2);               // 104 KB
  float* hdec   = (float*)alloc((size_t)NN * 4);                            // 0.4 MB
  float* vprep  = (float*)alloc(128 * 4);
  int* gcursor  = (int*)alloc((size_t)NBUCK * 4);

  k_prepw<<<97, 512, 0, stream>>>(Wenc, Wmsg, Wupd, Wdec, Wb, vprep, gcursor);
  k_enc2<<<ENCB, 512, 0, stream>>>(x, benc, bupd, Wdec, Wb, mNp, hdec);
  k_sortscatter<<<NCH, 512, 0, stream>>>(ei, ea, gcursor, csr);
  k_msg<<<NBUCK, 512, 0, stream>>>(mNp, Wmsg, gcursor, csr, bmsg, vprep, hdec, bdec, out);
}

// Round 14
// 124.941 us; speedup vs baseline: 1.0887x; 1.0887x over previous
//
#include <hip/hip_runtime.h>

#define NN 100000
#define NE 1600000
#define HID 128
#define NBUCK 1563          // ceil(NN/64), 64-node buckets
#define CAP 1280            // csr slots per bucket (Poisson(1024)+8 sigma)
#define STP 130             // padded LDS stride (f32 words) for min-state
#define SENT 3.0e38f
#define CH 8192             // edges per sort chunk
#define NCH 196             // ceil(NE/CH)
#define ENCB 391            // encoder blocks (256 rows each)

typedef float f32x4 __attribute__((ext_vector_type(4)));
typedef __bf16 bf16x8 __attribute__((ext_vector_type(8)));
typedef unsigned short u16x8 __attribute__((ext_vector_type(8)));

static __device__ __forceinline__ unsigned short f2bf(float f) {
  union { float f; unsigned u; } v; v.f = f;
  unsigned u = v.u;
  return (unsigned short)((u + 0x7FFFu + ((u >> 16) & 1u)) >> 16);
}

static __device__ __forceinline__ f32x4 mfma_bf16(u16x8 a, u16x8 b, f32x4 c) {
  return __builtin_amdgcn_mfma_f32_16x16x32_bf16(
      __builtin_bit_cast(bf16x8, a), __builtin_bit_cast(bf16x8, b), c, 0, 0, 0);
}

// edge_index may arrive as int32 or int64 (values < 2^31, little-endian).
static __device__ __forceinline__ int gidx(const int* __restrict__ ei, int is64, long long pos) {
  return is64 ? ei[pos * 2] : ei[pos];
}
// inline dtype detection: for int64, hi-words of src[0..63] are all zero
static __device__ __forceinline__ int detect64(const int* __restrict__ ei, int tid) {
  unsigned long long bl = __ballot(ei[2 * (tid & 63) + 1] == 0);
  return (bl == ~0ull) ? 1 : 0;
}

// ---------------- one-time prep: padded-bf16 weight image + vprep + gcursor init ----------------
// Wb[m][j*136+k] = bf16(W_m[k][j]);  vprep[k] = sum_j W_upd[128+k][j]*W_dec[j];  gcursor[b]=b*CAP
__global__ __launch_bounds__(512) void k_prepw(const float* __restrict__ Wenc,
    const float* __restrict__ Wmsg, const float* __restrict__ Wupd,
    const float* __restrict__ Wdec, unsigned short* __restrict__ Wb,
    float* __restrict__ vprep, int* __restrict__ gcursor) {
  int b = blockIdx.x;
  int t = threadIdx.x;
  if (b == 96) {
    if (t < 128) {
      const float* row = Wupd + (size_t)(128 + t) * 128;
      float s = 0.f;
#pragma unroll 8
      for (int j = 0; j < 128; ++j) s = fmaf(row[j], Wdec[j], s);
      vprep[t] = s;
    }
    for (int i = t; i < NBUCK; i += 512) gcursor[i] = i * CAP;
    return;
  }
  int i = b * 512 + t;                        // 0..49151
  int m = i >> 14, idx = i & 16383;
  const float* src = (m == 0) ? Wenc : ((m == 1) ? Wmsg : Wupd);
  int k = idx >> 7, j = idx & 127;
  Wb[m * 17408 + j * 136 + k] = f2bf(src[idx]);
}

// ---------------- merged: sort chunks (blocks 0..195) + encoder (blocks 196..586) ----------------
// No data dependency between the two paths; they share the machine concurrently.
__global__ __launch_bounds__(512, 4) void k_work(const float* __restrict__ x,
    const float* __restrict__ benc, const float* __restrict__ bupd,
    const float* __restrict__ Wdec, const unsigned short* __restrict__ Wb,
    const int* __restrict__ ei, const float* __restrict__ ea,
    int* __restrict__ gcursor, unsigned long long* __restrict__ csr,
    unsigned* __restrict__ mNp, float* __restrict__ hdec) {
  __shared__ __align__(16) unsigned short Wt[17408];        // 34.8 KB (one matrix)
  __shared__ unsigned short bounce[8][16 * 136];            // 34.8 KB
  __shared__ float bshE[128];
  __shared__ float bshU[128];
  __shared__ float wdsh[128];
  int tid = threadIdx.x;

  if (blockIdx.x < NCH) {
    // ========== sort path: chunk-sorted scatter into fixed-capacity bucket slots ==========
    // entry u64: (src*64) 23b @0 | local(6b) @23 | ea_bf16(16b) @48
    unsigned* cnt = (unsigned*)Wt;                          // 6.25 KB alias
    unsigned* gbase = (unsigned*)&bounce[0][0];             // 6.25 KB alias
    int chunk = blockIdx.x;
    long long base = (long long)chunk * CH;
    int n = (int)(((long long)NE - base < CH) ? ((long long)NE - base) : CH);
    int is64 = detect64(ei, tid);
    for (int i = tid; i < NBUCK; i += 512) cnt[i] = 0;
    __syncthreads();
    // pass 1: count; keep dst in registers
    int dreg[CH / 512];
#pragma unroll
    for (int k = 0; k < CH / 512; ++k) {
      int i = k * 512 + tid;
      if (i < n) {
        int d = gidx(ei, is64, (long long)NE + base + i);
        dreg[k] = d;
        atomicAdd(&cnt[d >> 6], 1u);
      } else dreg[k] = -1;
    }
    __syncthreads();
    // claim contiguous runs in each bucket's slot region
    for (int b = tid; b < NBUCK; b += 512) {
      unsigned c = cnt[b];
      gbase[b] = c ? (unsigned)atomicAdd(&gcursor[b], (int)c) : 0u;
    }
    __syncthreads();
    for (int i = tid; i < NBUCK; i += 512) cnt[i] = 0;      // reuse as local cursor
    __syncthreads();
    // pass 2: write entries (reads only src + ea)
#pragma unroll
    for (int k = 0; k < CH / 512; ++k) {
      int i = k * 512 + tid;
      int d = dreg[k];
      if (d >= 0) {
        int s = gidx(ei, is64, base + i);
        unsigned eab = f2bf(ea[base + i]);
        int b = d >> 6;
        unsigned lp = atomicAdd(&cnt[b], 1u);
        unsigned lo = (unsigned)(s << 6) | ((unsigned)(d & 63) << 23);
        csr[gbase[b] + lp] = (unsigned long long)lo | ((unsigned long long)eab << 48);
      }
    }
    return;
  }

  // ========== encoder path ==========
  int eb = blockIdx.x - NCH;                                // 0..390
  if (tid < 128) { bshE[tid] = benc[tid]; bshU[tid] = bupd[tid]; wdsh[tid] = Wdec[tid]; }

  int wave = tid >> 6, lane = tid & 63;
  int l15 = lane & 15, lg = lane >> 4;
  f32x4 zero = {0.f, 0.f, 0.f, 0.f};
  u16x8 haG[2][4];                                          // h frags for both row-groups

  // ---- stage E: h = relu(x @ W_enc + b_enc) ----
  for (int i = tid; i < 2176; i += 512)
    ((uint4*)Wt)[i] = ((const uint4*)Wb)[i];
  __syncthreads();
#pragma unroll
  for (int g = 0; g < 2; ++g) {
    int rowBase = eb * 256 + g * 128 + wave * 16;
    int nodeA = rowBase + l15; if (nodeA > NN - 1) nodeA = NN - 1;
    u16x8 af[4];
#pragma unroll
    for (int kt = 0; kt < 4; ++kt) {
      const float* px = x + (long long)nodeA * HID + kt * 32 + lg * 8;
      f32x4 a0 = *(const f32x4*)px;
      f32x4 a1 = *(const f32x4*)(px + 4);
      u16x8 t;
      t[0] = f2bf(a0[0]); t[1] = f2bf(a0[1]); t[2] = f2bf(a0[2]); t[3] = f2bf(a0[3]);
      t[4] = f2bf(a1[0]); t[5] = f2bf(a1[1]); t[6] = f2bf(a1[2]); t[7] = f2bf(a1[3]);
      af[kt] = t;
    }
    f32x4 acc[8];
#pragma unroll
    for (int nt = 0; nt < 8; ++nt) acc[nt] = zero;
#pragma unroll
    for (int kt = 0; kt < 4; ++kt)
#pragma unroll
      for (int nt = 0; nt < 8; ++nt) {
        u16x8 bfv = *(const u16x8*)&Wt[(nt * 16 + l15) * 136 + kt * 32 + lg * 8];
        acc[nt] = mfma_bf16(af[kt], bfv, acc[nt]);
      }
#pragma unroll
    for (int nt = 0; nt < 8; ++nt) {
      int j = nt * 16 + l15;
      float bj = bshE[j];
#pragma unroll
      for (int r = 0; r < 4; ++r) {
        float v = acc[nt][r] + bj;
        v = v > 0.f ? v : 0.f;
        bounce[wave][(lg * 4 + r) * 136 + j] = f2bf(v);
      }
    }
    asm volatile("s_waitcnt lgkmcnt(0)" ::: "memory");
    __builtin_amdgcn_sched_barrier(0);
#pragma unroll
    for (int kt = 0; kt < 4; ++kt)
      haG[g][kt] = *(const u16x8*)&bounce[wave][l15 * 136 + kt * 32 + lg * 8];
    asm volatile("s_waitcnt lgkmcnt(0)" ::: "memory");
    __builtin_amdgcn_sched_barrier(0);
  }
  __syncthreads();

  // ---- stage M: mN = h @ W_msg, permuted store ----
  for (int i = tid; i < 2176; i += 512)
    ((uint4*)Wt)[i] = ((const uint4*)Wb)[2176 + i];
  __syncthreads();
#pragma unroll
  for (int g = 0; g < 2; ++g) {
    int rowBase = eb * 256 + g * 128 + wave * 16;
    f32x4 acc2[8];
#pragma unroll
    for (int nt = 0; nt < 8; ++nt) acc2[nt] = zero;
#pragma unroll
    for (int kt = 0; kt < 4; ++kt)
#pragma unroll
      for (int nt = 0; nt < 8; ++nt) {
        u16x8 bfv = *(const u16x8*)&Wt[(nt * 16 + l15) * 136 + kt * 32 + lg * 8];
        acc2[nt] = mfma_bf16(haG[g][kt], bfv, acc2[nt]);
      }
#pragma unroll
    for (int nt = 0; nt < 8; ++nt) {
      int j = nt * 16 + l15;
#pragma unroll
      for (int r = 0; r < 4; ++r)
        bounce[wave][(lg * 4 + r) * 136 + j] = f2bf(acc2[nt][r]);
    }
    asm volatile("s_waitcnt lgkmcnt(0)" ::: "memory");
    __builtin_amdgcn_sched_barrier(0);
    // permuted store: word l = col l | col(l+64)<<16
#pragma unroll 4
    for (int row = 0; row < 16; ++row) {
      int node = rowBase + row;
      if (node < NN) {
        unsigned lo = bounce[wave][row * 136 + lane];
        unsigned hi = bounce[wave][row * 136 + 64 + lane];
        mNp[(size_t)node * 64 + lane] = lo | (hi << 16);
      }
    }
    asm volatile("s_waitcnt lgkmcnt(0)" ::: "memory");
    __builtin_amdgcn_sched_barrier(0);
  }
  __syncthreads();

  // ---- stage U: hdec = (h @ W_upd_top + b_upd) . W_dec ----
  for (int i = tid; i < 2176; i += 512)
    ((uint4*)Wt)[i] = ((const uint4*)Wb)[4352 + i];
  __syncthreads();
#pragma unroll
  for (int g = 0; g < 2; ++g) {
    int rowBase = eb * 256 + g * 128 + wave * 16;
    f32x4 acc3[8];
#pragma unroll
    for (int nt = 0; nt < 8; ++nt) acc3[nt] = zero;
#pragma unroll
    for (int kt = 0; kt < 4; ++kt)
#pragma unroll
      for (int nt = 0; nt < 8; ++nt) {
        u16x8 bfv = *(const u16x8*)&Wt[(nt * 16 + l15) * 136 + kt * 32 + lg * 8];
        acc3[nt] = mfma_bf16(haG[g][kt], bfv, acc3[nt]);
      }
    float hs0 = 0.f, hs1 = 0.f, hs2 = 0.f, hs3 = 0.f;
#pragma unroll
    for (int nt = 0; nt < 8; ++nt) {
      int j = nt * 16 + l15;
      float bu = bshU[j], wv = wdsh[j];
      hs0 += (acc3[nt][0] + bu) * wv;
      hs1 += (acc3[nt][1] + bu) * wv;
      hs2 += (acc3[nt][2] + bu) * wv;
      hs3 += (acc3[nt][3] + bu) * wv;
    }
#pragma unroll
    for (int m = 1; m < 16; m <<= 1) {
      hs0 += __shfl_xor(hs0, m);
      hs1 += __shfl_xor(hs1, m);
      hs2 += __shfl_xor(hs2, m);
      hs3 += __shfl_xor(hs3, m);
    }
    if (l15 == 0) {
      int n0 = rowBase + lg * 4;
      if (n0 + 3 < NN) {
        float4 st4; st4.x = hs0; st4.y = hs1; st4.z = hs2; st4.w = hs3;
        *(float4*)&hdec[n0] = st4;
      } else {
        if (n0 + 0 < NN) hdec[n0 + 0] = hs0;
        if (n0 + 1 < NN) hdec[n0 + 1] = hs1;
        if (n0 + 2 < NN) hdec[n0 + 2] = hs2;
        if (n0 + 3 < NN) hdec[n0 + 3] = hs3;
      }
    }
  }
}

// ---------------- fused: edge min (native f32 LDS atomicMin) + decoder dot + sigmoid ----------------
// Wave-uniform csr processing: loop bounds scalarized so csr loads/decodes go to SALU/SMEM.
__global__ __launch_bounds__(512, 8) void k_msg(const unsigned* __restrict__ mNp,
    const float* __restrict__ Wmsg, const int* __restrict__ gcursor,
    const unsigned long long* __restrict__ csr, const float* __restrict__ bmsg,
    const float* __restrict__ vprep, const float* __restrict__ hdec,
    const float* __restrict__ bdec, float* __restrict__ out) {
  __shared__ float stf[64 * STP];     // 33.3 KB, padded stride
  int tid = threadIdx.x;
  int b = blockIdx.x;
  for (int i = tid; i < 64 * STP; i += 512) stf[i] = SENT;
  __syncthreads();

  int lane = tid & 63;
  int wv = tid >> 6;                     // 0..7
  int off = b * CAP, end = gcursor[b];
  int cntE = end - off;
  int per = (cntE + 7) >> 3;
  int i0 = off + wv * per;
  int i1 = i0 + per; if (i1 > end) i1 = end;
  // wave-uniform loop bounds -> scalar loads for csr
  int iu = __builtin_amdgcn_readfirstlane(i0);
  int ie = __builtin_amdgcn_readfirstlane(i1);
  float wl0 = Wmsg[128 * 128 + lane];
  float wl1 = Wmsg[128 * 128 + 64 + lane];

#define EDGE_DO(PK, VV) do { \
    int loc_ = (int)(((unsigned)(PK) >> 23) & 0x3Fu); \
    float ea_ = __uint_as_float((unsigned)((PK) >> 32) & 0xFFFF0000u); \
    float a0_ = fmaf(ea_, wl0, __uint_as_float((VV) << 16)); \
    float a1_ = fmaf(ea_, wl1, __uint_as_float((VV) & 0xFFFF0000u)); \
    atomicMin(&stf[loc_ * STP + lane], a0_); \
    atomicMin(&stf[loc_ * STP + 64 + lane], a1_); \
  } while (0)

  int i = iu;
  for (; i + 16 <= ie; i += 16) {
    unsigned long long pk[16];
#pragma unroll
    for (int j = 0; j < 16; ++j) pk[j] = csr[i + j];
    unsigned v[16];
#pragma unroll
    for (int j = 0; j < 16; ++j)
      v[j] = mNp[((unsigned)pk[j] & 0x7FFFFFu) + lane];
#pragma unroll
    for (int j = 0; j < 16; ++j) EDGE_DO(pk[j], v[j]);
  }
  for (; i + 4 <= ie; i += 4) {
    unsigned long long pk[4];
#pragma unroll
    for (int j = 0; j < 4; ++j) pk[j] = csr[i + j];
    unsigned v[4];
#pragma unroll
    for (int j = 0; j < 4; ++j)
      v[j] = mNp[((unsigned)pk[j] & 0x7FFFFFu) + lane];
#pragma unroll
    for (int j = 0; j < 4; ++j) EDGE_DO(pk[j], v[j]);
  }
  for (; i < ie; ++i) {
    unsigned long long pk = csr[i];
    unsigned v = mNp[((unsigned)pk & 0x7FFFFFu) + lane];
    EDGE_DO(pk, v);
  }
#undef EDGE_DO
  __syncthreads();

  // ---- phase 2: out[node] = sigmoid((agg+bmsg).v + hdec + bdec) ----
  float vl0 = vprep[lane], vl1 = vprep[64 + lane];
  float bm0 = bmsg[lane], bm1 = bmsg[64 + lane];
  float bd = *bdec;
#pragma unroll
  for (int q = 0; q < 8; ++q) {
    int loc = (wv << 3) + q;
    float s0 = stf[loc * STP + lane];
    float s1 = stf[loc * STP + 64 + lane];
    float ps = ((s0 < 1.0e30f) ? (s0 + bm0) * vl0 : 0.f)
             + ((s1 < 1.0e30f) ? (s1 + bm1) * vl1 : 0.f);
#pragma unroll
    for (int m = 1; m < 64; m <<= 1) ps += __shfl_xor(ps, m);
    if (lane == 0) {
      int node = (b << 6) + loc;
      if (node < NN)
        out[node] = 1.f / (1.f + expf(-(ps + hdec[node] + bd)));
    }
  }
}

extern "C" void kernel_launch(void* const* d_in, const int* in_sizes, int n_in,
                              void* d_out, int out_size, void* d_ws, size_t ws_size,
                              hipStream_t stream) {
  const float* x    = (const float*)d_in[0];
  const int*   ei   = (const int*)d_in[1];
  const float* ea   = (const float*)d_in[2];
  const float* Wenc = (const float*)d_in[3];
  const float* benc = (const float*)d_in[4];
  const float* Wmsg = (const float*)d_in[5];
  const float* bmsg = (const float*)d_in[6];
  const float* Wupd = (const float*)d_in[7];
  const float* bupd = (const float*)d_in[8];
  const float* Wdec = (const float*)d_in[9];
  const float* bdec = (const float*)d_in[10];
  float* out = (float*)d_out;

  // workspace carve (total ~42.2 MiB, well below the empirically-safe 65.2 MB)
  char* w = (char*)d_ws;
  auto alloc = [&](size_t bytes) { char* p = w; w += (bytes + 255) & ~(size_t)255; return p; };
  unsigned* mNp        = (unsigned*)alloc((size_t)NN * 64 * 4);             // 25.6 MB
  unsigned long long* csr = (unsigned long long*)alloc((size_t)NBUCK * CAP * 8); // 16.0 MB
  unsigned short* Wb = (unsigned short*)alloc(3 * 17408 * 2);               // 104 KB
  float* hdec   = (float*)alloc((size_t)NN * 4);                            // 0.4 MB
  float* vprep  = (float*)alloc(128 * 4);
  int* gcursor  = (int*)alloc((size_t)NBUCK * 4);

  k_prepw<<<97, 512, 0, stream>>>(Wenc, Wmsg, Wupd, Wdec, Wb, vprep, gcursor);
  k_work<<<NCH + ENCB, 512, 0, stream>>>(x, benc, bupd, Wdec, Wb, ei, ea,
                                         gcursor, csr, mNp, hdec);
  k_msg<<<NBUCK, 512, 0, stream>>>(mNp, Wmsg, gcursor, csr, bmsg, vprep, hdec, bdec, out);
}

// Round 15
// 117.259 us; speedup vs baseline: 1.1601x; 1.0655x over previous
//
#include <hip/hip_runtime.h>

#define NN 100000
#define NE 1600000
#define HID 128
#define NBUCK 1563          // ceil(NN/64), 64-node buckets
#define CAP 1280            // csr slots per bucket (Poisson(1024)+8 sigma)
#define STP 130             // padded LDS stride (f32 words) for min-state
#define SENT 3.0e38f
#define CH 4096             // edges per sort chunk (one chunk per encoder block)
#define ENCB 391            // blocks: 256 encoder rows + 1 sort chunk each

typedef float f32x4 __attribute__((ext_vector_type(4)));
typedef __bf16 bf16x8 __attribute__((ext_vector_type(8)));
typedef unsigned short u16x8 __attribute__((ext_vector_type(8)));

static __device__ __forceinline__ unsigned short f2bf(float f) {
  union { float f; unsigned u; } v; v.f = f;
  unsigned u = v.u;
  return (unsigned short)((u + 0x7FFFu + ((u >> 16) & 1u)) >> 16);
}

static __device__ __forceinline__ f32x4 mfma_bf16(u16x8 a, u16x8 b, f32x4 c) {
  return __builtin_amdgcn_mfma_f32_16x16x32_bf16(
      __builtin_bit_cast(bf16x8, a), __builtin_bit_cast(bf16x8, b), c, 0, 0, 0);
}

// edge_index may arrive as int32 or int64 (values < 2^31, little-endian).
static __device__ __forceinline__ int gidx(const int* __restrict__ ei, int is64, long long pos) {
  return is64 ? ei[pos * 2] : ei[pos];
}
// inline dtype detection: for int64, hi-words of src[0..63] are all zero
static __device__ __forceinline__ int detect64(const int* __restrict__ ei, int tid) {
  unsigned long long bl = __ballot(ei[2 * (tid & 63) + 1] == 0);
  return (bl == ~0ull) ? 1 : 0;
}

// ---------------- one-time prep: padded-bf16 weight image + vprep + gcursor init ----------------
// Wb[m][j*136+k] = bf16(W_m[k][j]);  vprep[k] = sum_j W_upd[128+k][j]*W_dec[j];  gcursor[b]=b*CAP
__global__ __launch_bounds__(512) void k_prepw(const float* __restrict__ Wenc,
    const float* __restrict__ Wmsg, const float* __restrict__ Wupd,
    const float* __restrict__ Wdec, unsigned short* __restrict__ Wb,
    float* __restrict__ vprep, int* __restrict__ gcursor) {
  int b = blockIdx.x;
  int t = threadIdx.x;
  if (b == 96) {
    if (t < 128) {
      const float* row = Wupd + (size_t)(128 + t) * 128;
      float s = 0.f;
#pragma unroll 8
      for (int j = 0; j < 128; ++j) s = fmaf(row[j], Wdec[j], s);
      vprep[t] = s;
    }
    for (int i = t; i < NBUCK; i += 512) gcursor[i] = i * CAP;
    return;
  }
  int i = b * 512 + t;                        // 0..49151
  int m = i >> 14, idx = i & 16383;
  const float* src = (m == 0) ? Wenc : ((m == 1) ? Wmsg : Wupd);
  int k = idx >> 7, j = idx & 127;
  Wb[m * 17408 + j * 136 + k] = f2bf(src[idx]);
}

// ---------------- every block: encoder (256 rows) THEN its own sort chunk (4096 edges) ----------------
__global__ __launch_bounds__(512, 4) void k_work(const float* __restrict__ x,
    const float* __restrict__ benc, const float* __restrict__ bupd,
    const float* __restrict__ Wdec, const unsigned short* __restrict__ Wb,
    const int* __restrict__ ei, const float* __restrict__ ea,
    int* __restrict__ gcursor, unsigned long long* __restrict__ csr,
    unsigned* __restrict__ mNp, float* __restrict__ hdec) {
  __shared__ __align__(16) unsigned short Wt[17408];        // 34.8 KB (one matrix)
  __shared__ unsigned short bounce[8][16 * 136];            // 34.8 KB
  __shared__ float bshE[128];
  __shared__ float bshU[128];
  __shared__ float wdsh[128];
  int tid = threadIdx.x;
  int eb = blockIdx.x;

  if (tid < 128) { bshE[tid] = benc[tid]; bshU[tid] = bupd[tid]; wdsh[tid] = Wdec[tid]; }

  int wave = tid >> 6, lane = tid & 63;
  int l15 = lane & 15, lg = lane >> 4;
  f32x4 zero = {0.f, 0.f, 0.f, 0.f};
  u16x8 haG[2][4];                                          // h frags for both row-groups

  // ---- stage E: h = relu(x @ W_enc + b_enc) ----
  for (int i = tid; i < 2176; i += 512)
    ((uint4*)Wt)[i] = ((const uint4*)Wb)[i];
  __syncthreads();
#pragma unroll
  for (int g = 0; g < 2; ++g) {
    int rowBase = eb * 256 + g * 128 + wave * 16;
    int nodeA = rowBase + l15; if (nodeA > NN - 1) nodeA = NN - 1;
    u16x8 af[4];
#pragma unroll
    for (int kt = 0; kt < 4; ++kt) {
      const float* px = x + (long long)nodeA * HID + kt * 32 + lg * 8;
      f32x4 a0 = *(const f32x4*)px;
      f32x4 a1 = *(const f32x4*)(px + 4);
      u16x8 t;
      t[0] = f2bf(a0[0]); t[1] = f2bf(a0[1]); t[2] = f2bf(a0[2]); t[3] = f2bf(a0[3]);
      t[4] = f2bf(a1[0]); t[5] = f2bf(a1[1]); t[6] = f2bf(a1[2]); t[7] = f2bf(a1[3]);
      af[kt] = t;
    }
    f32x4 acc[8];
#pragma unroll
    for (int nt = 0; nt < 8; ++nt) acc[nt] = zero;
#pragma unroll
    for (int kt = 0; kt < 4; ++kt)
#pragma unroll
      for (int nt = 0; nt < 8; ++nt) {
        u16x8 bfv = *(const u16x8*)&Wt[(nt * 16 + l15) * 136 + kt * 32 + lg * 8];
        acc[nt] = mfma_bf16(af[kt], bfv, acc[nt]);
      }
#pragma unroll
    for (int nt = 0; nt < 8; ++nt) {
      int j = nt * 16 + l15;
      float bj = bshE[j];
#pragma unroll
      for (int r = 0; r < 4; ++r) {
        float v = acc[nt][r] + bj;
        v = v > 0.f ? v : 0.f;
        bounce[wave][(lg * 4 + r) * 136 + j] = f2bf(v);
      }
    }
    asm volatile("s_waitcnt lgkmcnt(0)" ::: "memory");
    __builtin_amdgcn_sched_barrier(0);
#pragma unroll
    for (int kt = 0; kt < 4; ++kt)
      haG[g][kt] = *(const u16x8*)&bounce[wave][l15 * 136 + kt * 32 + lg * 8];
    asm volatile("s_waitcnt lgkmcnt(0)" ::: "memory");
    __builtin_amdgcn_sched_barrier(0);
  }
  __syncthreads();

  // ---- stage M: mN = h @ W_msg, permuted store ----
  for (int i = tid; i < 2176; i += 512)
    ((uint4*)Wt)[i] = ((const uint4*)Wb)[2176 + i];
  __syncthreads();
#pragma unroll
  for (int g = 0; g < 2; ++g) {
    int rowBase = eb * 256 + g * 128 + wave * 16;
    f32x4 acc2[8];
#pragma unroll
    for (int nt = 0; nt < 8; ++nt) acc2[nt] = zero;
#pragma unroll
    for (int kt = 0; kt < 4; ++kt)
#pragma unroll
      for (int nt = 0; nt < 8; ++nt) {
        u16x8 bfv = *(const u16x8*)&Wt[(nt * 16 + l15) * 136 + kt * 32 + lg * 8];
        acc2[nt] = mfma_bf16(haG[g][kt], bfv, acc2[nt]);
      }
#pragma unroll
    for (int nt = 0; nt < 8; ++nt) {
      int j = nt * 16 + l15;
#pragma unroll
      for (int r = 0; r < 4; ++r)
        bounce[wave][(lg * 4 + r) * 136 + j] = f2bf(acc2[nt][r]);
    }
    asm volatile("s_waitcnt lgkmcnt(0)" ::: "memory");
    __builtin_amdgcn_sched_barrier(0);
    // permuted store: word l = col l | col(l+64)<<16
#pragma unroll 4
    for (int row = 0; row < 16; ++row) {
      int node = rowBase + row;
      if (node < NN) {
        unsigned lo = bounce[wave][row * 136 + lane];
        unsigned hi = bounce[wave][row * 136 + 64 + lane];
        mNp[(size_t)node * 64 + lane] = lo | (hi << 16);
      }
    }
    asm volatile("s_waitcnt lgkmcnt(0)" ::: "memory");
    __builtin_amdgcn_sched_barrier(0);
  }
  __syncthreads();

  // ---- stage U: hdec = (h @ W_upd_top + b_upd) . W_dec ----
  for (int i = tid; i < 2176; i += 512)
    ((uint4*)Wt)[i] = ((const uint4*)Wb)[4352 + i];
  __syncthreads();
#pragma unroll
  for (int g = 0; g < 2; ++g) {
    int rowBase = eb * 256 + g * 128 + wave * 16;
    f32x4 acc3[8];
#pragma unroll
    for (int nt = 0; nt < 8; ++nt) acc3[nt] = zero;
#pragma unroll
    for (int kt = 0; kt < 4; ++kt)
#pragma unroll
      for (int nt = 0; nt < 8; ++nt) {
        u16x8 bfv = *(const u16x8*)&Wt[(nt * 16 + l15) * 136 + kt * 32 + lg * 8];
        acc3[nt] = mfma_bf16(haG[g][kt], bfv, acc3[nt]);
      }
    float hs0 = 0.f, hs1 = 0.f, hs2 = 0.f, hs3 = 0.f;
#pragma unroll
    for (int nt = 0; nt < 8; ++nt) {
      int j = nt * 16 + l15;
      float bu = bshU[j], wv = wdsh[j];
      hs0 += (acc3[nt][0] + bu) * wv;
      hs1 += (acc3[nt][1] + bu) * wv;
      hs2 += (acc3[nt][2] + bu) * wv;
      hs3 += (acc3[nt][3] + bu) * wv;
    }
#pragma unroll
    for (int m = 1; m < 16; m <<= 1) {
      hs0 += __shfl_xor(hs0, m);
      hs1 += __shfl_xor(hs1, m);
      hs2 += __shfl_xor(hs2, m);
      hs3 += __shfl_xor(hs3, m);
    }
    if (l15 == 0) {
      int n0 = rowBase + lg * 4;
      if (n0 + 3 < NN) {
        float4 st4; st4.x = hs0; st4.y = hs1; st4.z = hs2; st4.w = hs3;
        *(float4*)&hdec[n0] = st4;
      } else {
        if (n0 + 0 < NN) hdec[n0 + 0] = hs0;
        if (n0 + 1 < NN) hdec[n0 + 1] = hs1;
        if (n0 + 2 < NN) hdec[n0 + 2] = hs2;
        if (n0 + 3 < NN) hdec[n0 + 3] = hs3;
      }
    }
  }
  __syncthreads();

  // ========== sort phase: this block's 4096-edge chunk -> bucket slot regions ==========
  // entry u64: (src*64) 23b @0 | local(6b) @23 | ea_bf16(16b) @48
  {
    unsigned* cnt = (unsigned*)Wt;                          // 6.25 KB alias (weights dead)
    unsigned* gbase = (unsigned*)&bounce[0][0];             // 6.25 KB alias
    int chunk = eb;
    long long base = (long long)chunk * CH;
    int n = (int)(((long long)NE - base < CH) ? ((long long)NE - base) : CH);
    if (n < 0) n = 0;
    int is64 = detect64(ei, tid);
    for (int i = tid; i < NBUCK; i += 512) cnt[i] = 0;
    __syncthreads();
    // pass 1: count; keep dst in registers
    int dreg[CH / 512];
#pragma unroll
    for (int k = 0; k < CH / 512; ++k) {
      int i = k * 512 + tid;
      if (i < n) {
        int d = gidx(ei, is64, (long long)NE + base + i);
        dreg[k] = d;
        atomicAdd(&cnt[d >> 6], 1u);
      } else dreg[k] = -1;
    }
    __syncthreads();
    // claim contiguous runs in each bucket's slot region
    for (int b = tid; b < NBUCK; b += 512) {
      unsigned c = cnt[b];
      gbase[b] = c ? (unsigned)atomicAdd(&gcursor[b], (int)c) : 0u;
    }
    __syncthreads();
    for (int i = tid; i < NBUCK; i += 512) cnt[i] = 0;      // reuse as local cursor
    __syncthreads();
    // pass 2: write entries (reads only src + ea)
#pragma unroll
    for (int k = 0; k < CH / 512; ++k) {
      int i = k * 512 + tid;
      int d = dreg[k];
      if (d >= 0) {
        int s = gidx(ei, is64, base + i);
        unsigned eab = f2bf(ea[base + i]);
        int b = d >> 6;
        unsigned lp = atomicAdd(&cnt[b], 1u);
        unsigned lo = (unsigned)(s << 6) | ((unsigned)(d & 63) << 23);
        csr[gbase[b] + lp] = (unsigned long long)lo | ((unsigned long long)eab << 48);
      }
    }
  }
}

// ---------------- fused: edge min (native f32 LDS atomicMin) + decoder dot + sigmoid ----------------
// Wave-uniform csr processing: loop bounds scalarized so csr loads/decodes go to SALU/SMEM.
__global__ __launch_bounds__(512, 8) void k_msg(const unsigned* __restrict__ mNp,
    const float* __restrict__ Wmsg, const int* __restrict__ gcursor,
    const unsigned long long* __restrict__ csr, const float* __restrict__ bmsg,
    const float* __restrict__ vprep, const float* __restrict__ hdec,
    const float* __restrict__ bdec, float* __restrict__ out) {
  __shared__ float stf[64 * STP];     // 33.3 KB, padded stride
  int tid = threadIdx.x;
  int b = blockIdx.x;
  for (int i = tid; i < 64 * STP; i += 512) stf[i] = SENT;
  __syncthreads();

  int lane = tid & 63;
  int wv = tid >> 6;                     // 0..7
  int off = b * CAP, end = gcursor[b];
  int cntE = end - off;
  int per = (cntE + 7) >> 3;
  int i0 = off + wv * per;
  int i1 = i0 + per; if (i1 > end) i1 = end;
  // wave-uniform loop bounds -> scalar loads for csr
  int iu = __builtin_amdgcn_readfirstlane(i0);
  int ie = __builtin_amdgcn_readfirstlane(i1);
  float wl0 = Wmsg[128 * 128 + lane];
  float wl1 = Wmsg[128 * 128 + 64 + lane];

#define EDGE_DO(PK, VV) do { \
    int loc_ = (int)(((unsigned)(PK) >> 23) & 0x3Fu); \
    float ea_ = __uint_as_float((unsigned)((PK) >> 32) & 0xFFFF0000u); \
    float a0_ = fmaf(ea_, wl0, __uint_as_float((VV) << 16)); \
    float a1_ = fmaf(ea_, wl1, __uint_as_float((VV) & 0xFFFF0000u)); \
    atomicMin(&stf[loc_ * STP + lane], a0_); \
    atomicMin(&stf[loc_ * STP + 64 + lane], a1_); \
  } while (0)

  int i = iu;
  for (; i + 16 <= ie; i += 16) {
    unsigned long long pk[16];
#pragma unroll
    for (int j = 0; j < 16; ++j) pk[j] = csr[i + j];
    unsigned v[16];
#pragma unroll
    for (int j = 0; j < 16; ++j)
      v[j] = mNp[((unsigned)pk[j] & 0x7FFFFFu) + lane];
#pragma unroll
    for (int j = 0; j < 16; ++j) EDGE_DO(pk[j], v[j]);
  }
  for (; i + 4 <= ie; i += 4) {
    unsigned long long pk[4];
#pragma unroll
    for (int j = 0; j < 4; ++j) pk[j] = csr[i + j];
    unsigned v[4];
#pragma unroll
    for (int j = 0; j < 4; ++j)
      v[j] = mNp[((unsigned)pk[j] & 0x7FFFFFu) + lane];
#pragma unroll
    for (int j = 0; j < 4; ++j) EDGE_DO(pk[j], v[j]);
  }
  for (; i < ie; ++i) {
    unsigned long long pk = csr[i];
    unsigned v = mNp[((unsigned)pk & 0x7FFFFFu) + lane];
    EDGE_DO(pk, v);
  }
#undef EDGE_DO
  __syncthreads();

  // ---- phase 2: out[node] = sigmoid((agg+bmsg).v + hdec + bdec) ----
  float vl0 = vprep[lane], vl1 = vprep[64 + lane];
  float bm0 = bmsg[lane], bm1 = bmsg[64 + lane];
  float bd = *bdec;
#pragma unroll
  for (int q = 0; q < 8; ++q) {
    int loc = (wv << 3) + q;
    float s0 = stf[loc * STP + lane];
    float s1 = stf[loc * STP + 64 + lane];
    float ps = ((s0 < 1.0e30f) ? (s0 + bm0) * vl0 : 0.f)
             + ((s1 < 1.0e30f) ? (s1 + bm1) * vl1 : 0.f);
#pragma unroll
    for (int m = 1; m < 64; m <<= 1) ps += __shfl_xor(ps, m);
    if (lane == 0) {
      int node = (b << 6) + loc;
      if (node < NN)
        out[node] = 1.f / (1.f + expf(-(ps + hdec[node] + bd)));
    }
  }
}

extern "C" void kernel_launch(void* const* d_in, const int* in_sizes, int n_in,
                              void* d_out, int out_size, void* d_ws, size_t ws_size,
                              hipStream_t stream) {
  const float* x    = (const float*)d_in[0];
  const int*   ei   = (const int*)d_in[1];
  const float* ea   = (const float*)d_in[2];
  const float* Wenc = (const float*)d_in[3];
  const float* benc = (const float*)d_in[4];
  const float* Wmsg = (const float*)d_in[5];
  const float* bmsg = (const float*)d_in[6];
  const float* Wupd = (const float*)d_in[7];
  const float* bupd = (const float*)d_in[8];
  const float* Wdec = (const float*)d_in[9];
  const float* bdec = (const float*)d_in[10];
  float* out = (float*)d_out;

  // workspace carve (total ~42.2 MiB, well below the empirically-safe 65.2 MB)
  char* w = (char*)d_ws;
  auto alloc = [&](size_t bytes) { char* p = w; w += (bytes + 255) & ~(size_t)255; return p; };
  unsigned* mNp        = (unsigned*)alloc((size_t)NN * 64 * 4);             // 25.6 MB
  unsigned long long* csr = (unsigned long long*)alloc((size_t)NBUCK * CAP * 8); // 16.0 MB
  unsigned short* Wb = (unsigned short*)alloc(3 * 17408 * 2);               // 104 KB
  float* hdec   = (float*)alloc((size_t)NN * 4);                            // 0.4 MB
  float* vprep  = (float*)alloc(128 * 4);
  int* gcursor  = (int*)alloc((size_t)NBUCK * 4);

  k_prepw<<<97, 512, 0, stream>>>(Wenc, Wmsg, Wupd, Wdec, Wb, vprep, gcursor);
  k_work<<<ENCB, 512, 0, stream>>>(x, benc, bupd, Wdec, Wb, ei, ea,
                                   gcursor, csr, mNp, hdec);
  k_msg<<<NBUCK, 512, 0, stream>>>(mNp, Wmsg, gcursor, csr, bmsg, vprep, hdec, bdec, out);
}

// Round 16
// 113.419 us; speedup vs baseline: 1.1993x; 1.0339x over previous
//
#include <hip/hip_runtime.h>

#define NN 100000
#define NE 1600000
#define HID 128
#define NBUCK 1563          // ceil(NN/64), 64-node buckets
#define CAP 1280            // csr slots per bucket (Poisson(1024)+8 sigma)
#define STP 130             // padded LDS stride (f32 words) for min-state
#define SENT 3.0e38f
#define CH 4096             // edges per sort chunk (one chunk per block)
#define ENCB 391            // blocks: 256 encoder rows + 1 sort chunk each

typedef float f32x4 __attribute__((ext_vector_type(4)));
typedef __bf16 bf16x8 __attribute__((ext_vector_type(8)));
typedef unsigned short u16x8 __attribute__((ext_vector_type(8)));

static __device__ __forceinline__ unsigned short f2bf(float f) {
  union { float f; unsigned u; } v; v.f = f;
  unsigned u = v.u;
  return (unsigned short)((u + 0x7FFFu + ((u >> 16) & 1u)) >> 16);
}

static __device__ __forceinline__ f32x4 mfma_bf16(u16x8 a, u16x8 b, f32x4 c) {
  return __builtin_amdgcn_mfma_f32_16x16x32_bf16(
      __builtin_bit_cast(bf16x8, a), __builtin_bit_cast(bf16x8, b), c, 0, 0, 0);
}

// edge_index may arrive as int32 or int64 (values < 2^31, little-endian).
static __device__ __forceinline__ int gidx(const int* __restrict__ ei, int is64, long long pos) {
  return is64 ? ei[pos * 2] : ei[pos];
}
// inline dtype detection: for int64, hi-words of src[0..63] are all zero
static __device__ __forceinline__ int detect64(const int* __restrict__ ei, int tid) {
  unsigned long long bl = __ballot(ei[2 * (tid & 63) + 1] == 0);
  return (bl == ~0ull) ? 1 : 0;
}

// ---------------- one-time prep: padded-bf16 weight image + vprep + gcursor init ----------------
// Wb[m][j*136+k] = bf16(W_m[k][j]);  vprep[k] = sum_j W_upd[128+k][j]*W_dec[j];  gcursor[b]=b*CAP
__global__ __launch_bounds__(512) void k_prepw(const float* __restrict__ Wenc,
    const float* __restrict__ Wmsg, const float* __restrict__ Wupd,
    const float* __restrict__ Wdec, unsigned short* __restrict__ Wb,
    float* __restrict__ vprep, int* __restrict__ gcursor) {
  int b = blockIdx.x;
  int t = threadIdx.x;
  if (b == 96) {
    if (t < 128) {
      const float* row = Wupd + (size_t)(128 + t) * 128;
      float s = 0.f;
#pragma unroll 8
      for (int j = 0; j < 128; ++j) s = fmaf(row[j], Wdec[j], s);
      vprep[t] = s;
    }
    for (int i = t; i < NBUCK; i += 512) gcursor[i] = i * CAP;
    return;
  }
  int i = b * 512 + t;                        // 0..49151
  int m = i >> 14, idx = i & 16383;
  const float* src = (m == 0) ? Wenc : ((m == 1) ? Wmsg : Wupd);
  int k = idx >> 7, j = idx & 127;
  Wb[m * 17408 + j * 136 + k] = f2bf(src[idx]);
}

// ---------------- every block: encoder (256 rows) with its sort chunk interleaved ----------------
// Edge pass-1 (loads + count + entry build) issues after stage E so its latency
// hides under stages M/U; pass-2 (claim + write) is read-free at the tail.
__global__ __launch_bounds__(512, 4) void k_work(const float* __restrict__ x,
    const float* __restrict__ benc, const float* __restrict__ bupd,
    const float* __restrict__ Wdec, const unsigned short* __restrict__ Wb,
    const int* __restrict__ ei, const float* __restrict__ ea,
    int* __restrict__ gcursor, unsigned long long* __restrict__ csr,
    unsigned* __restrict__ mNp, float* __restrict__ hdec) {
  __shared__ __align__(16) unsigned short Wt[17408];        // 34.8 KB (one matrix)
  __shared__ unsigned short bounce[8][16 * 136];            // 34.8 KB
  __shared__ unsigned cnt[NBUCK];                           // 6.25 KB (persistent)
  __shared__ float bshE[128];
  __shared__ float bshU[128];
  __shared__ float wdsh[128];
  int tid = threadIdx.x;
  int eb = blockIdx.x;

  for (int i = tid; i < NBUCK; i += 512) cnt[i] = 0;
  if (tid < 128) { bshE[tid] = benc[tid]; bshU[tid] = bupd[tid]; wdsh[tid] = Wdec[tid]; }

  int wave = tid >> 6, lane = tid & 63;
  int l15 = lane & 15, lg = lane >> 4;
  f32x4 zero = {0.f, 0.f, 0.f, 0.f};
  u16x8 haG[2][4];                                          // h frags for both row-groups

  // ---- stage E: h = relu(x @ W_enc + b_enc) ----
  for (int i = tid; i < 2176; i += 512)
    ((uint4*)Wt)[i] = ((const uint4*)Wb)[i];
  __syncthreads();
#pragma unroll
  for (int g = 0; g < 2; ++g) {
    int rowBase = eb * 256 + g * 128 + wave * 16;
    int nodeA = rowBase + l15; if (nodeA > NN - 1) nodeA = NN - 1;
    u16x8 af[4];
#pragma unroll
    for (int kt = 0; kt < 4; ++kt) {
      const float* px = x + (long long)nodeA * HID + kt * 32 + lg * 8;
      f32x4 a0 = *(const f32x4*)px;
      f32x4 a1 = *(const f32x4*)(px + 4);
      u16x8 t;
      t[0] = f2bf(a0[0]); t[1] = f2bf(a0[1]); t[2] = f2bf(a0[2]); t[3] = f2bf(a0[3]);
      t[4] = f2bf(a1[0]); t[5] = f2bf(a1[1]); t[6] = f2bf(a1[2]); t[7] = f2bf(a1[3]);
      af[kt] = t;
    }
    f32x4 acc[8];
#pragma unroll
    for (int nt = 0; nt < 8; ++nt) acc[nt] = zero;
#pragma unroll
    for (int kt = 0; kt < 4; ++kt)
#pragma unroll
      for (int nt = 0; nt < 8; ++nt) {
        u16x8 bfv = *(const u16x8*)&Wt[(nt * 16 + l15) * 136 + kt * 32 + lg * 8];
        acc[nt] = mfma_bf16(af[kt], bfv, acc[nt]);
      }
#pragma unroll
    for (int nt = 0; nt < 8; ++nt) {
      int j = nt * 16 + l15;
      float bj = bshE[j];
#pragma unroll
      for (int r = 0; r < 4; ++r) {
        float v = acc[nt][r] + bj;
        v = v > 0.f ? v : 0.f;
        bounce[wave][(lg * 4 + r) * 136 + j] = f2bf(v);
      }
    }
    asm volatile("s_waitcnt lgkmcnt(0)" ::: "memory");
    __builtin_amdgcn_sched_barrier(0);
#pragma unroll
    for (int kt = 0; kt < 4; ++kt)
      haG[g][kt] = *(const u16x8*)&bounce[wave][l15 * 136 + kt * 32 + lg * 8];
    asm volatile("s_waitcnt lgkmcnt(0)" ::: "memory");
    __builtin_amdgcn_sched_barrier(0);
  }

  // ---- edge pass 1: load src/dst/ea, build full csr entries in registers, count ----
  // entry u64: (src*64) 23b @0 | local(6b) @23 | bucket(16b) @32 | ea_bf16(16b) @48
  // (k_msg masks hi[15:0] off, so the bucket field is harmless in csr.)
  unsigned long long ereg[CH / 512];
  {
    long long base = (long long)eb * CH;
    int n = (int)(((long long)NE - base < CH) ? ((long long)NE - base) : CH);
    if (n < 0) n = 0;
    int is64 = detect64(ei, tid);
#pragma unroll
    for (int k = 0; k < CH / 512; ++k) {
      int i = k * 512 + tid;
      if (i < n) {
        int s = gidx(ei, is64, base + i);
        int d = gidx(ei, is64, (long long)NE + base + i);
        unsigned eab = f2bf(ea[base + i]);
        unsigned bkt = (unsigned)(d >> 6);
        unsigned lo = (unsigned)(s << 6) | ((unsigned)(d & 63) << 23);
        unsigned hi = (eab << 16) | bkt;
        ereg[k] = (unsigned long long)lo | ((unsigned long long)hi << 32);
        atomicAdd(&cnt[bkt], 1u);
      } else ereg[k] = 0xFFFFFFFFFFFFFFFFull;     // bucket field 0xFFFF = invalid
    }
  }
  __syncthreads();

  // ---- stage M: mN = h @ W_msg, permuted store ----
  for (int i = tid; i < 2176; i += 512)
    ((uint4*)Wt)[i] = ((const uint4*)Wb)[2176 + i];
  __syncthreads();
#pragma unroll
  for (int g = 0; g < 2; ++g) {
    int rowBase = eb * 256 + g * 128 + wave * 16;
    f32x4 acc2[8];
#pragma unroll
    for (int nt = 0; nt < 8; ++nt) acc2[nt] = zero;
#pragma unroll
    for (int kt = 0; kt < 4; ++kt)
#pragma unroll
      for (int nt = 0; nt < 8; ++nt) {
        u16x8 bfv = *(const u16x8*)&Wt[(nt * 16 + l15) * 136 + kt * 32 + lg * 8];
        acc2[nt] = mfma_bf16(haG[g][kt], bfv, acc2[nt]);
      }
#pragma unroll
    for (int nt = 0; nt < 8; ++nt) {
      int j = nt * 16 + l15;
#pragma unroll
      for (int r = 0; r < 4; ++r)
        bounce[wave][(lg * 4 + r) * 136 + j] = f2bf(acc2[nt][r]);
    }
    asm volatile("s_waitcnt lgkmcnt(0)" ::: "memory");
    __builtin_amdgcn_sched_barrier(0);
    // permuted store: word l = col l | col(l+64)<<16
#pragma unroll 4
    for (int row = 0; row < 16; ++row) {
      int node = rowBase + row;
      if (node < NN) {
        unsigned lo = bounce[wave][row * 136 + lane];
        unsigned hi = bounce[wave][row * 136 + 64 + lane];
        mNp[(size_t)node * 64 + lane] = lo | (hi << 16);
      }
    }
    asm volatile("s_waitcnt lgkmcnt(0)" ::: "memory");
    __builtin_amdgcn_sched_barrier(0);
  }
  __syncthreads();

  // ---- stage U: hdec = (h @ W_upd_top + b_upd) . W_dec ----
  for (int i = tid; i < 2176; i += 512)
    ((uint4*)Wt)[i] = ((const uint4*)Wb)[4352 + i];
  __syncthreads();
#pragma unroll
  for (int g = 0; g < 2; ++g) {
    int rowBase = eb * 256 + g * 128 + wave * 16;
    f32x4 acc3[8];
#pragma unroll
    for (int nt = 0; nt < 8; ++nt) acc3[nt] = zero;
#pragma unroll
    for (int kt = 0; kt < 4; ++kt)
#pragma unroll
      for (int nt = 0; nt < 8; ++nt) {
        u16x8 bfv = *(const u16x8*)&Wt[(nt * 16 + l15) * 136 + kt * 32 + lg * 8];
        acc3[nt] = mfma_bf16(haG[g][kt], bfv, acc3[nt]);
      }
    float hs0 = 0.f, hs1 = 0.f, hs2 = 0.f, hs3 = 0.f;
#pragma unroll
    for (int nt = 0; nt < 8; ++nt) {
      int j = nt * 16 + l15;
      float bu = bshU[j], wv = wdsh[j];
      hs0 += (acc3[nt][0] + bu) * wv;
      hs1 += (acc3[nt][1] + bu) * wv;
      hs2 += (acc3[nt][2] + bu) * wv;
      hs3 += (acc3[nt][3] + bu) * wv;
    }
#pragma unroll
    for (int m = 1; m < 16; m <<= 1) {
      hs0 += __shfl_xor(hs0, m);
      hs1 += __shfl_xor(hs1, m);
      hs2 += __shfl_xor(hs2, m);
      hs3 += __shfl_xor(hs3, m);
    }
    if (l15 == 0) {
      int n0 = rowBase + lg * 4;
      if (n0 + 3 < NN) {
        float4 st4; st4.x = hs0; st4.y = hs1; st4.z = hs2; st4.w = hs3;
        *(float4*)&hdec[n0] = st4;
      } else {
        if (n0 + 0 < NN) hdec[n0 + 0] = hs0;
        if (n0 + 1 < NN) hdec[n0 + 1] = hs1;
        if (n0 + 2 < NN) hdec[n0 + 2] = hs2;
        if (n0 + 3 < NN) hdec[n0 + 3] = hs3;
      }
    }
  }
  __syncthreads();   // stage-U Wt reads + all pass-1 cnt atomics complete

  // ---- edge pass 2: claim runs, write register-held entries (zero global reads) ----
  {
    unsigned* gbase = (unsigned*)&bounce[0][0];             // bounce is dead now
    for (int b = tid; b < NBUCK; b += 512) {
      unsigned c = cnt[b];
      gbase[b] = c ? (unsigned)atomicAdd(&gcursor[b], (int)c) : 0u;
    }
    __syncthreads();
    for (int i = tid; i < NBUCK; i += 512) cnt[i] = 0;      // reuse as local cursor
    __syncthreads();
#pragma unroll
    for (int k = 0; k < CH / 512; ++k) {
      unsigned long long e = ereg[k];
      unsigned bkt = (unsigned)(e >> 32) & 0xFFFFu;
      if (bkt != 0xFFFFu) {
        unsigned lp = atomicAdd(&cnt[bkt], 1u);
        csr[gbase[bkt] + lp] = e;
      }
    }
  }
}

// ---------------- fused: edge min (native f32 LDS atomicMin) + decoder dot + sigmoid ----------------
// Wave-uniform csr processing: loop bounds scalarized so csr loads/decodes go to SALU/SMEM.
__global__ __launch_bounds__(512, 8) void k_msg(const unsigned* __restrict__ mNp,
    const float* __restrict__ Wmsg, const int* __restrict__ gcursor,
    const unsigned long long* __restrict__ csr, const float* __restrict__ bmsg,
    const float* __restrict__ vprep, const float* __restrict__ hdec,
    const float* __restrict__ bdec, float* __restrict__ out) {
  __shared__ float stf[64 * STP];     // 33.3 KB, padded stride
  int tid = threadIdx.x;
  int b = blockIdx.x;
  for (int i = tid; i < 64 * STP; i += 512) stf[i] = SENT;
  __syncthreads();

  int lane = tid & 63;
  int wv = tid >> 6;                     // 0..7
  int off = b * CAP, end = gcursor[b];
  int cntE = end - off;
  int per = (cntE + 7) >> 3;
  int i0 = off + wv * per;
  int i1 = i0 + per; if (i1 > end) i1 = end;
  // wave-uniform loop bounds -> scalar loads for csr
  int iu = __builtin_amdgcn_readfirstlane(i0);
  int ie = __builtin_amdgcn_readfirstlane(i1);
  float wl0 = Wmsg[128 * 128 + lane];
  float wl1 = Wmsg[128 * 128 + 64 + lane];

#define EDGE_DO(PK, VV) do { \
    int loc_ = (int)(((unsigned)(PK) >> 23) & 0x3Fu); \
    float ea_ = __uint_as_float((unsigned)((PK) >> 32) & 0xFFFF0000u); \
    float a0_ = fmaf(ea_, wl0, __uint_as_float((VV) << 16)); \
    float a1_ = fmaf(ea_, wl1, __uint_as_float((VV) & 0xFFFF0000u)); \
    atomicMin(&stf[loc_ * STP + lane], a0_); \
    atomicMin(&stf[loc_ * STP + 64 + lane], a1_); \
  } while (0)

  int i = iu;
  for (; i + 16 <= ie; i += 16) {
    unsigned long long pk[16];
#pragma unroll
    for (int j = 0; j < 16; ++j) pk[j] = csr[i + j];
    unsigned v[16];
#pragma unroll
    for (int j = 0; j < 16; ++j)
      v[j] = mNp[((unsigned)pk[j] & 0x7FFFFFu) + lane];
#pragma unroll
    for (int j = 0; j < 16; ++j) EDGE_DO(pk[j], v[j]);
  }
  for (; i + 4 <= ie; i += 4) {
    unsigned long long pk[4];
#pragma unroll
    for (int j = 0; j < 4; ++j) pk[j] = csr[i + j];
    unsigned v[4];
#pragma unroll
    for (int j = 0; j < 4; ++j)
      v[j] = mNp[((unsigned)pk[j] & 0x7FFFFFu) + lane];
#pragma unroll
    for (int j = 0; j < 4; ++j) EDGE_DO(pk[j], v[j]);
  }
  for (; i < ie; ++i) {
    unsigned long long pk = csr[i];
    unsigned v = mNp[((unsigned)pk & 0x7FFFFFu) + lane];
    EDGE_DO(pk, v);
  }
#undef EDGE_DO
  __syncthreads();

  // ---- phase 2: out[node] = sigmoid((agg+bmsg).v + hdec + bdec) ----
  float vl0 = vprep[lane], vl1 = vprep[64 + lane];
  float bm0 = bmsg[lane], bm1 = bmsg[64 + lane];
  float bd = *bdec;
#pragma unroll
  for (int q = 0; q < 8; ++q) {
    int loc = (wv << 3) + q;
    float s0 = stf[loc * STP + lane];
    float s1 = stf[loc * STP + 64 + lane];
    float ps = ((s0 < 1.0e30f) ? (s0 + bm0) * vl0 : 0.f)
             + ((s1 < 1.0e30f) ? (s1 + bm1) * vl1 : 0.f);
#pragma unroll
    for (int m = 1; m < 64; m <<= 1) ps += __shfl_xor(ps, m);
    if (lane == 0) {
      int node = (b << 6) + loc;
      if (node < NN)
        out[node] = 1.f / (1.f + expf(-(ps + hdec[node] + bd)));
    }
  }
}

extern "C" void kernel_launch(void* const* d_in, const int* in_sizes, int n_in,
                              void* d_out, int out_size, void* d_ws, size_t ws_size,
                              hipStream_t stream) {
  const float* x    = (const float*)d_in[0];
  const int*   ei   = (const int*)d_in[1];
  const float* ea   = (const float*)d_in[2];
  const float* Wenc = (const float*)d_in[3];
  const float* benc = (const float*)d_in[4];
  const float* Wmsg = (const float*)d_in[5];
  const float* bmsg = (const float*)d_in[6];
  const float* Wupd = (const float*)d_in[7];
  const float* bupd = (const float*)d_in[8];
  const float* Wdec = (const float*)d_in[9];
  const float* bdec = (const float*)d_in[10];
  float* out = (float*)d_out;

  // workspace carve (total ~42.2 MiB, well below the empirically-safe 65.2 MB)
  char* w = (char*)d_ws;
  auto alloc = [&](size_t bytes) { char* p = w; w += (bytes + 255) & ~(size_t)255; return p; };
  unsigned* mNp        = (unsigned*)alloc((size_t)NN * 64 * 4);             // 25.6 MB
  unsigned long long* csr = (unsigned long long*)alloc((size_t)NBUCK * CAP * 8); // 16.0 MB
  unsigned short* Wb = (unsigned short*)alloc(3 * 17408 * 2);               // 104 KB
  float* hdec   = (float*)alloc((size_t)NN * 4);                            // 0.4 MB
  float* vprep  = (float*)alloc(128 * 4);
  int* gcursor  = (int*)alloc((size_t)NBUCK * 4);

  k_prepw<<<97, 512, 0, stream>>>(Wenc, Wmsg, Wupd, Wdec, Wb, vprep, gcursor);
  k_work<<<ENCB, 512, 0, stream>>>(x, benc, bupd, Wdec, Wb, ei, ea,
                                   gcursor, csr, mNp, hdec);
  k_msg<<<NBUCK, 512, 0, stream>>>(mNp, Wmsg, gcursor, csr, bmsg, vprep, hdec, bdec, out);
}